// Round 7
// baseline (323.459 us; speedup 1.0000x reference)
//
#include <hip/hip_runtime.h>

// MultiHeadattention: B=2, S=2048, D=1024, H=16, Dk=64.
// QUIRK: softmax over the HEAD axis (dim=1): attn[b,h,q,k] = exp(s)/sum_h' exp(s').
// R7: (1) SCALE folded into Q projection (osc=0.125) -> one fewer VALU per exp in
// zker2/attn4; (2) attn4 drops lrz (no cross-wave reuse; direct uint4 rz loads),
// LDS 16KB, KS=4 -> 8 blocks/CU (attn was VALU-bound at 30% occupancy);
// zker2 drops lQ (per-wave data; direct Q-frag loads); (3) QKV GEMMs fused into
// one 1536-block dispatch, W-converts fused into one.

#define D_MODEL 1024
#define NH 16
#define DKH 64
#define SEQ 2048
#define NB 2
#define NTOK (NB * SEQ)

typedef float f32x4 __attribute__((ext_vector_type(4)));
typedef short bf16x8 __attribute__((ext_vector_type(8)));

static __device__ __forceinline__ unsigned short f2bf(float x) {
    union { float f; unsigned int u; } c; c.f = x;
    unsigned int r = (c.u + 0x7FFFu + ((c.u >> 16) & 1u)) >> 16;
    return (unsigned short)r;
}
static __device__ __forceinline__ unsigned int pack2(float a, float b) {
    return (unsigned int)f2bf(a) | ((unsigned int)f2bf(b) << 16);
}
static __device__ __forceinline__ unsigned int pack2rn(float a, float b) {
    union { float f; unsigned int u; } ca, cb; ca.f = a; cb.f = b;
    return __builtin_amdgcn_perm(cb.u + 0x8000u, ca.u + 0x8000u, 0x07060302u);
}
static __device__ __forceinline__ float bflo(unsigned int u) {
    union { unsigned int x; float f; } c; c.x = u << 16; return c.f;
}
static __device__ __forceinline__ float bfhi(unsigned int u) {
    union { unsigned int x; float f; } c; c.x = u & 0xFFFF0000u; return c.f;
}
static __device__ __forceinline__ f32x4 mfma16(uint4 a, uint4 b, f32x4 c) {
    return __builtin_amdgcn_mfma_f32_16x16x32_bf16(
        __builtin_bit_cast(bf16x8, a), __builtin_bit_cast(bf16x8, b), c, 0, 0, 0);
}
static __device__ __forceinline__ void gl_lds16(const unsigned short* g, unsigned short* l) {
    __builtin_amdgcn_global_load_lds(
        (const __attribute__((address_space(1))) unsigned int*)g,
        (__attribute__((address_space(3))) unsigned int*)l, 16, 0, 0);
}
static __device__ __forceinline__ int fsw(int row) {
    return (row & 7) ^ ((row >> 2) & 7);
}

// ---------------- fp32 -> bf16: x ----------------
__global__ __launch_bounds__(256) void cvt_k(const float* __restrict__ x,
                                             unsigned short* __restrict__ xb)
{
    size_t i = ((size_t)blockIdx.x * 256 + threadIdx.x) * 8;
    float4 a = *(const float4*)(x + i);
    float4 b = *(const float4*)(x + i + 4);
    uint4 p = { pack2(a.x, a.y), pack2(a.z, a.w), pack2(b.x, b.y), pack2(b.z, b.w) };
    *(uint4*)(xb + i) = p;
}

// ---------------- fp32 -> bf16: all three W's in one dispatch ----------------
__global__ __launch_bounds__(256) void cvt_w3(
    const float* __restrict__ w0, const float* __restrict__ w1,
    const float* __restrict__ w2, unsigned short* __restrict__ outb)
{
    int sel = blockIdx.x >> 9;               // 512 blocks per matrix
    int blk = blockIdx.x & 511;
    const float* src = (sel == 0) ? w0 : (sel == 1) ? w1 : w2;
    size_t i = ((size_t)blk * 256 + threadIdx.x) * 8;
    float4 a = *(const float4*)(src + i);
    float4 b = *(const float4*)(src + i + 4);
    uint4 p = { pack2(a.x, a.y), pack2(a.z, a.w), pack2(b.x, b.y), pack2(b.z, b.w) };
    *(uint4*)(outb + (size_t)sel * D_MODEL * D_MODEL + i) = p;
}

// ---------------- fused QKV GEMM: one dispatch, sel = blockIdx.x/16 ----------------
// out[m,n] = (sum_k xb[m,k]*Wb[n,k] + bias[n]) * osc
// sel 0: Q -> per-head, osc=0.125; sel 1: K -> per-head; sel 2: V -> Vt transpose.
__global__ __launch_bounds__(256) void gemm_qkv3(
    const unsigned short* __restrict__ A, const unsigned short* __restrict__ Wb3,
    const float* __restrict__ bq, const float* __restrict__ bk,
    const float* __restrict__ bv, unsigned short* __restrict__ Qh,
    unsigned short* __restrict__ Kh, unsigned short* __restrict__ Vt)
{
    __shared__ unsigned short lA[128 * 64];
    __shared__ unsigned short lB[64 * 64];
    const int tid = threadIdx.x;
    const int wv = tid >> 6, lane = tid & 63, quad = lane >> 4, lm = lane & 15;
    const int sel = blockIdx.x >> 4;
    const int m0 = blockIdx.y * 128, n0 = (blockIdx.x & 15) * 64;
    const int sub = lane >> 3, chl = (lane & 7) ^ sub;
    const unsigned short* Wb = Wb3 + (size_t)sel * D_MODEL * D_MODEL;
    const float* bias = (sel == 0) ? bq : (sel == 1) ? bk : bv;
    const float osc = (sel == 0) ? 0.125f : 1.0f;

    f32x4 acc[2][4] = {};

    for (int k0 = 0; k0 < D_MODEL; k0 += 64) {
        __syncthreads();
#pragma unroll
        for (int j = 0; j < 4; ++j) {
            int rbase = wv * 32 + j * 8;
            gl_lds16(A + (size_t)(m0 + rbase + sub) * D_MODEL + k0 + chl * 8,
                     &lA[rbase * 64]);
        }
#pragma unroll
        for (int j = 0; j < 2; ++j) {
            int rbase = wv * 16 + j * 8;
            gl_lds16(Wb + (size_t)(n0 + rbase + sub) * D_MODEL + k0 + chl * 8,
                     &lB[rbase * 64]);
        }
        __syncthreads();
#pragma unroll
        for (int ks = 0; ks < 2; ++ks) {
            uint4 af[2];
#pragma unroll
            for (int mt = 0; mt < 2; ++mt)
                af[mt] = *(const uint4*)&lA[(wv * 32 + mt * 16 + lm) * 64 +
                                            ((ks * 4 + quad) ^ (lm & 7)) * 8];
#pragma unroll
            for (int nt = 0; nt < 4; ++nt) {
                uint4 bf = *(const uint4*)&lB[(nt * 16 + lm) * 64 +
                                              ((ks * 4 + quad) ^ (lm & 7)) * 8];
                acc[0][nt] = mfma16(af[0], bf, acc[0][nt]);
                acc[1][nt] = mfma16(af[1], bf, acc[1][nt]);
            }
        }
    }

    if (sel < 2) {
        unsigned short* out = (sel == 0) ? Qh : Kh;
        const int h = n0 >> 6;
#pragma unroll
        for (int nt = 0; nt < 4; ++nt) {
            float bvv = bias[n0 + nt * 16 + lm];
            int d = nt * 16 + lm;
#pragma unroll
            for (int mt = 0; mt < 2; ++mt)
#pragma unroll
                for (int r = 0; r < 4; ++r) {
                    int m = m0 + wv * 32 + mt * 16 + quad * 4 + r;
                    int b = m >> 11, q = m & 2047;
                    out[((size_t)(b * NH + h) * SEQ + q) * DKH + d] =
                        f2bf((acc[mt][nt][r] + bvv) * osc);
                }
        }
    } else {
        __syncthreads();
        unsigned short* T = lA;
#pragma unroll
        for (int nt = 0; nt < 4; ++nt) {
            float bvv = bias[n0 + nt * 16 + lm];
            int nl = nt * 16 + lm;
#pragma unroll
            for (int mt = 0; mt < 2; ++mt) {
                int ml = wv * 32 + mt * 16 + quad * 4;
                uint2 p = { pack2rn(acc[mt][nt][0] + bvv, acc[mt][nt][1] + bvv),
                            pack2rn(acc[mt][nt][2] + bvv, acc[mt][nt][3] + bvv) };
                *(uint2*)&T[nl * 128 + ml] = p;
            }
        }
        __syncthreads();
        int row = tid >> 2, seg = tid & 3;
        int b = m0 >> 11, s0 = m0 & 2047;
        unsigned short* dst = Vt + ((size_t)(b * D_MODEL) + n0 + row) * SEQ + s0 + seg * 32;
        const unsigned short* src = &T[row * 128 + seg * 32];
#pragma unroll
        for (int i = 0; i < 4; ++i)
            *(uint4*)(dst + i * 8) = *(const uint4*)(src + i * 8);
    }
}

// ---------------- out-proj: ctx = sum of KS per-head partials; fp32 out ----------------
template <int KS>
__global__ __launch_bounds__(256) void gemm_osum(
    const unsigned short* __restrict__ OP, const float* __restrict__ W,
    const float* __restrict__ bias, float* __restrict__ out)
{
    __shared__ unsigned short lA[128 * 64];
    __shared__ unsigned short lB[64 * 64];
    const int tid = threadIdx.x;
    const int wv = tid >> 6, lane = tid & 63, quad = lane >> 4, lm = lane & 15;
    const int m0 = blockIdx.y * 128, n0 = blockIdx.x * 64;
    const size_t M = (size_t)NTOK * D_MODEL;
    const int brow = tid >> 2, bpart = tid & 3;

    f32x4 acc[2][4] = {};

    for (int k0 = 0; k0 < D_MODEL; k0 += 64) {
        const int h = k0 >> 6;
        __syncthreads();
#pragma unroll
        for (int r = 0; r < 4; ++r) {
            int idx = r * 256 + tid;
            int row = idx >> 3, ch = idx & 7, phys = ch ^ (row & 7);
            int m = m0 + row, b = m >> 11, q = m & 2047;
            size_t base = ((size_t)(b * NH + h) * SEQ + q) * DKH + ch * 8;
            uint4 u = *(const uint4*)(OP + base);
            float lo0 = bflo(u.x), hi0 = bfhi(u.x), lo1 = bflo(u.y), hi1 = bfhi(u.y);
            float lo2 = bflo(u.z), hi2 = bfhi(u.z), lo3 = bflo(u.w), hi3 = bfhi(u.w);
#pragma unroll
            for (int p = 1; p < KS; ++p) {
                uint4 v = *(const uint4*)(OP + p * M + base);
                lo0 += bflo(v.x); hi0 += bfhi(v.x); lo1 += bflo(v.y); hi1 += bfhi(v.y);
                lo2 += bflo(v.z); hi2 += bfhi(v.z); lo3 += bflo(v.w); hi3 += bfhi(v.w);
            }
            uint4 pa = { pack2(lo0, hi0), pack2(lo1, hi1), pack2(lo2, hi2), pack2(lo3, hi3) };
            *(uint4*)&lA[row * 64 + phys * 8] = pa;
        }
        {
            const float* gb = W + (size_t)(n0 + brow) * D_MODEL + k0 + bpart * 16;
            float4 f0 = *(const float4*)gb;
            float4 f1 = *(const float4*)(gb + 4);
            float4 f2 = *(const float4*)(gb + 8);
            float4 f3 = *(const float4*)(gb + 12);
            uint4 p0 = { pack2(f0.x, f0.y), pack2(f0.z, f0.w), pack2(f1.x, f1.y), pack2(f1.z, f1.w) };
            uint4 p1 = { pack2(f2.x, f2.y), pack2(f2.z, f2.w), pack2(f3.x, f3.y), pack2(f3.z, f3.w) };
            int c0 = (bpart * 2) ^ (brow & 7), c1 = (bpart * 2 + 1) ^ (brow & 7);
            *(uint4*)&lB[brow * 64 + c0 * 8] = p0;
            *(uint4*)&lB[brow * 64 + c1 * 8] = p1;
        }
        __syncthreads();
#pragma unroll
        for (int ks = 0; ks < 2; ++ks) {
            uint4 af[2];
#pragma unroll
            for (int mt = 0; mt < 2; ++mt)
                af[mt] = *(const uint4*)&lA[(wv * 32 + mt * 16 + lm) * 64 +
                                            ((ks * 4 + quad) ^ (lm & 7)) * 8];
#pragma unroll
            for (int nt = 0; nt < 4; ++nt) {
                uint4 bf = *(const uint4*)&lB[(nt * 16 + lm) * 64 +
                                              ((ks * 4 + quad) ^ (lm & 7)) * 8];
                acc[0][nt] = mfma16(af[0], bf, acc[0][nt]);
                acc[1][nt] = mfma16(af[1], bf, acc[1][nt]);
            }
        }
    }
#pragma unroll
    for (int nt = 0; nt < 4; ++nt) {
        int n = n0 + nt * 16 + lm;
        float bv = bias[n];
#pragma unroll
        for (int mt = 0; mt < 2; ++mt)
#pragma unroll
            for (int r = 0; r < 4; ++r) {
                int m = m0 + wv * 32 + mt * 16 + quad * 4 + r;
                out[(size_t)m * D_MODEL + n] = acc[mt][nt][r] + bv;
            }
    }
}

// ---------------- zker2: rz[b][q][k] = 1/sum_h exp(S_scaled), K LDS-staged ----------------
// Block 128q x 128k; per h: stage K slab (16 KB, shared), Q-frags direct (per-wave).
__global__ __launch_bounds__(256) void zker2(
    const unsigned short* __restrict__ Qh, const unsigned short* __restrict__ Kh,
    unsigned short* __restrict__ rz)
{
    __shared__ unsigned short lK[128 * 64];  // 16 KB
    const int tid = threadIdx.x;
    const int wv = tid >> 6, lane = tid & 63, quad = lane >> 4, lm = lane & 15;
    const int q0 = blockIdx.x * 128, k0 = blockIdx.y * 128, b = blockIdx.z;
    const int srow = tid >> 3, sc = tid & 7;

    f32x4 z[2][8] = {};

    for (int h = 0; h < NH; ++h) {
        const size_t kb = ((size_t)(b * NH + h) * SEQ + k0) * DKH;
        __syncthreads();
#pragma unroll
        for (int j = 0; j < 4; ++j) {
            int row = j * 32 + srow;
            int g = sc ^ fsw(row);
            gl_lds16(Kh + kb + (size_t)row * 64 + g * 8, &lK[(j * 32 + wv * 8) * 64]);
        }
        // Q fragments direct (per-wave rows, reused across 8 kt)
        uint4 bq[2][2];
#pragma unroll
        for (int qs = 0; qs < 2; ++qs) {
            const unsigned short* qp = Qh +
                ((size_t)(b * NH + h) * SEQ + q0 + wv * 32 + qs * 16 + lm) * DKH + quad * 8;
            bq[qs][0] = *(const uint4*)qp;
            bq[qs][1] = *(const uint4*)(qp + 32);
        }
        __syncthreads();
#pragma unroll
        for (int kt = 0; kt < 8; ++kt) {
            int krow = kt * 16 + lm;
            uint4 a0 = *(const uint4*)&lK[krow * 64 + ((quad) ^ fsw(krow)) * 8];
            uint4 a1 = *(const uint4*)&lK[krow * 64 + ((4 + quad) ^ fsw(krow)) * 8];
#pragma unroll
            for (int qs = 0; qs < 2; ++qs) {
                f32x4 sf = {0.f, 0.f, 0.f, 0.f};
                sf = mfma16(a0, bq[qs][0], sf);
                sf = mfma16(a1, bq[qs][1], sf);
#pragma unroll
                for (int r = 0; r < 4; ++r)
                    z[qs][kt][r] += __expf(sf[r]);   // SCALE pre-folded into Q
            }
        }
    }
#pragma unroll
    for (int qs = 0; qs < 2; ++qs) {
        int q = q0 + wv * 32 + qs * 16 + lm;
#pragma unroll
        for (int kt = 0; kt < 8; ++kt) {
            int k = k0 + kt * 16 + quad * 4;
            uint2 st = { pack2rn(1.0f / z[qs][kt][0], 1.0f / z[qs][kt][1]),
                         pack2rn(1.0f / z[qs][kt][2], 1.0f / z[qs][kt][3]) };
            *(uint2*)(rz + (size_t)(b * SEQ + q) * SEQ + k) = st;
        }
    }
}

// ---------------- attn4: per-head attention; K/Vt LDS-staged, rz direct ----------------
template <int KS>
__global__ __launch_bounds__(256) void attn4(
    const unsigned short* __restrict__ Qh, const unsigned short* __restrict__ Kh,
    const unsigned short* __restrict__ Vt, const unsigned short* __restrict__ rz,
    unsigned short* __restrict__ OP)
{
    __shared__ unsigned short lK[64 * 64];   // 8 KB
    __shared__ unsigned short lV[64 * 64];   // 8 KB
    const int tid = threadIdx.x;
    const int wv = tid >> 6, lane = tid & 63, quad = lane >> 4, lm = lane & 15;
    const int q0 = blockIdx.x * 128;
    const int bh = blockIdx.y, b = bh >> 4, h = bh & 15;
    const int ksl = blockIdx.z;
    const int NIT = (SEQ / KS) / 64;
    const int kbeg = ksl * (SEQ / KS);
    const int q0w = q0 + wv * 32;
    const size_t hb = (size_t)(b * NH + h) * SEQ;
    const int srow = tid >> 3, sc = tid & 7;

    uint4 qf[2][2];
#pragma unroll
    for (int qs = 0; qs < 2; ++qs)
#pragma unroll
        for (int ks = 0; ks < 2; ++ks)
            qf[qs][ks] = *(const uint4*)(Qh + (hb + q0w + qs * 16 + lm) * DKH +
                                         ks * 32 + quad * 8);

    const int perm = ((lm >> 2) * 8) + (lm & 3);
    f32x4 oa[4][2] = {};

    for (int kt = 0; kt < NIT; ++kt) {
        const int kbase = kbeg + kt * 64;
        __syncthreads();
#pragma unroll
        for (int j = 0; j < 2; ++j) {
            int row = j * 32 + srow;
            int g = sc ^ fsw(row);
            gl_lds16(Kh + (hb + kbase + row) * DKH + g * 8,
                     &lK[(j * 32 + wv * 8) * 64]);
        }
#pragma unroll
        for (int j = 0; j < 2; ++j) {
            int row = j * 32 + srow;
            int g = sc ^ fsw(row);
            gl_lds16(Vt + ((size_t)(b * D_MODEL) + h * DKH + row) * SEQ + kbase + g * 8,
                     &lV[(j * 32 + wv * 8) * 64]);
        }
        // rz direct loads (no cross-wave reuse; overlaps with staging wait)
        uint4 rv[2][2];
#pragma unroll
        for (int qs = 0; qs < 2; ++qs)
#pragma unroll
            for (int gr = 0; gr < 2; ++gr)
                rv[gr][qs] = *(const uint4*)(rz +
                    (size_t)(b * SEQ + q0w + qs * 16 + lm) * SEQ +
                    kbase + gr * 32 + quad * 8);
        __syncthreads();

#pragma unroll
        for (int gr = 0; gr < 2; ++gr) {
            f32x4 sf[2][2] = {};
#pragma unroll
            for (int sel = 0; sel < 2; ++sel) {
                int key = gr * 32 + perm + sel * 4;
#pragma unroll
                for (int ks = 0; ks < 2; ++ks) {
                    uint4 kfv = *(const uint4*)&lK[key * 64 +
                                                   ((ks * 4 + quad) ^ fsw(key)) * 8];
                    sf[sel][0] = mfma16(kfv, qf[0][ks], sf[sel][0]);
                    sf[sel][1] = mfma16(kfv, qf[1][ks], sf[sel][1]);
                }
            }
            uint4 pk[2];
#pragma unroll
            for (int qs = 0; qs < 2; ++qs) {
                uint4 rq = rv[gr][qs];
                float p00 = __expf(sf[0][qs][0]) * bflo(rq.x);
                float p01 = __expf(sf[0][qs][1]) * bfhi(rq.x);
                float p02 = __expf(sf[0][qs][2]) * bflo(rq.y);
                float p03 = __expf(sf[0][qs][3]) * bfhi(rq.y);
                float p10 = __expf(sf[1][qs][0]) * bflo(rq.z);
                float p11 = __expf(sf[1][qs][1]) * bfhi(rq.z);
                float p12 = __expf(sf[1][qs][2]) * bflo(rq.w);
                float p13 = __expf(sf[1][qs][3]) * bfhi(rq.w);
                pk[qs].x = pack2rn(p00, p01);
                pk[qs].y = pack2rn(p02, p03);
                pk[qs].z = pack2rn(p10, p11);
                pk[qs].w = pack2rn(p12, p13);
            }
#pragma unroll
            for (int ct = 0; ct < 4; ++ct) {
                int vrow = ct * 16 + lm;
                uint4 vfv = *(const uint4*)&lV[vrow * 64 +
                                               ((gr * 4 + quad) ^ fsw(vrow)) * 8];
                oa[ct][0] = mfma16(vfv, pk[0], oa[ct][0]);
                oa[ct][1] = mfma16(vfv, pk[1], oa[ct][1]);
            }
        }
    }

    unsigned short* op = OP + (size_t)ksl * NTOK * D_MODEL;
#pragma unroll
    for (int ct = 0; ct < 4; ++ct)
#pragma unroll
        for (int qs = 0; qs < 2; ++qs) {
            uint2 st = { pack2rn(oa[ct][qs][0], oa[ct][qs][1]),
                         pack2rn(oa[ct][qs][2], oa[ct][qs][3]) };
            *(uint2*)(op + (hb + q0w + qs * 16 + lm) * DKH + ct * 16 + quad * 4) = st;
        }
}

extern "C" void kernel_launch(void* const* d_in, const int* in_sizes, int n_in,
                              void* d_out, int out_size, void* d_ws, size_t ws_size,
                              hipStream_t stream)
{
    const float* x  = (const float*)d_in[0];
    const float* Wq = (const float*)d_in[1];
    const float* bq = (const float*)d_in[2];
    const float* Wk = (const float*)d_in[3];
    const float* bk = (const float*)d_in[4];
    const float* Wv = (const float*)d_in[5];
    const float* bv = (const float*)d_in[6];
    const float* Wo = (const float*)d_in[7];
    const float* bo = (const float*)d_in[8];
    float* out = (float*)d_out;

    const size_t M  = (size_t)NTOK * D_MODEL;      // 4,194,304
    const size_t RZ = (size_t)NB * SEQ * SEQ;      // 8,388,608
    unsigned short* ws = (unsigned short*)d_ws;
    unsigned short* rzb = ws;            // aliases xb (xb dead after projs)
    unsigned short* xb  = ws;
    unsigned short* Qh  = ws + RZ;       // per-head [(b,h,q)][dk], Q pre-scaled by 1/8
    unsigned short* Kh  = Qh + M;
    unsigned short* Vt  = Kh + M;        // [b][c][s]
    unsigned short* OP  = Vt + M;        // KS per-head partials; early alias: Wb3
    unsigned short* Wb3 = OP;            // 3 bf16 weight matrices (dead before OP writes)

    const size_t need4 = (RZ + 3 * M + 4 * M) * sizeof(unsigned short);  // 75.5 MB
    const size_t need2 = (RZ + 3 * M + 2 * M) * sizeof(unsigned short);  // 58.7 MB
    const int KS = (ws_size >= need4) ? 4 : (ws_size >= need2) ? 2 : 1;

    cvt_k<<<2048, 256, 0, stream>>>(x, xb);
    cvt_w3<<<1536, 256, 0, stream>>>(Wq, Wk, Wv, Wb3);
    gemm_qkv3<<<dim3(48, 32), 256, 0, stream>>>(xb, Wb3, bq, bk, bv, Qh, Kh, Vt);
    zker2<<<dim3(16, 16, NB), 256, 0, stream>>>(Qh, Kh, rzb);
    dim3 gg(16, 32);
    if (KS == 4) {
        attn4<4><<<dim3(16, NB * NH, 4), 256, 0, stream>>>(Qh, Kh, Vt, rzb, OP);
        gemm_osum<4><<<gg, 256, 0, stream>>>(OP, Wo, bo, out);
    } else if (KS == 2) {
        attn4<2><<<dim3(16, NB * NH, 2), 256, 0, stream>>>(Qh, Kh, Vt, rzb, OP);
        gemm_osum<2><<<gg, 256, 0, stream>>>(OP, Wo, bo, out);
    } else {
        attn4<1><<<dim3(16, NB * NH, 1), 256, 0, stream>>>(Qh, Kh, Vt, rzb, OP);
        gemm_osum<1><<<gg, 256, 0, stream>>>(OP, Wo, bo, out);
    }
}

// Round 8
// 276.815 us; speedup vs baseline: 1.1685x; 1.1685x over previous
//
#include <hip/hip_runtime.h>

// MultiHeadattention: B=2, S=2048, D=1024, H=16, Dk=64.
// QUIRK: softmax over the HEAD axis (dim=1): attn[b,h,q,k] = exp(s)/sum_h' exp(s').
// R8: (1) partial fold un-fused from out-proj (R7's in-GEMM fold re-read 4 partials
// x16 n-blocks = 512 MB nominal -> 92 us); psum streams once. (2) Wo pre-converted
// to bf16 (into dead rz region) -> out-proj B staged via global_load_lds like QKV.
// (3) all GEMMs upgraded to 128x128 tiles (32 KB LDS, m93->m97 ladder direction).

#define D_MODEL 1024
#define NH 16
#define DKH 64
#define SEQ 2048
#define NB 2
#define NTOK (NB * SEQ)

typedef float f32x4 __attribute__((ext_vector_type(4)));
typedef short bf16x8 __attribute__((ext_vector_type(8)));

static __device__ __forceinline__ unsigned short f2bf(float x) {
    union { float f; unsigned int u; } c; c.f = x;
    unsigned int r = (c.u + 0x7FFFu + ((c.u >> 16) & 1u)) >> 16;
    return (unsigned short)r;
}
static __device__ __forceinline__ unsigned int pack2(float a, float b) {
    return (unsigned int)f2bf(a) | ((unsigned int)f2bf(b) << 16);
}
static __device__ __forceinline__ unsigned int pack2rn(float a, float b) {
    union { float f; unsigned int u; } ca, cb; ca.f = a; cb.f = b;
    return __builtin_amdgcn_perm(cb.u + 0x8000u, ca.u + 0x8000u, 0x07060302u);
}
static __device__ __forceinline__ float bflo(unsigned int u) {
    union { unsigned int x; float f; } c; c.x = u << 16; return c.f;
}
static __device__ __forceinline__ float bfhi(unsigned int u) {
    union { unsigned int x; float f; } c; c.x = u & 0xFFFF0000u; return c.f;
}
static __device__ __forceinline__ f32x4 mfma16(uint4 a, uint4 b, f32x4 c) {
    return __builtin_amdgcn_mfma_f32_16x16x32_bf16(
        __builtin_bit_cast(bf16x8, a), __builtin_bit_cast(bf16x8, b), c, 0, 0, 0);
}
static __device__ __forceinline__ void gl_lds16(const unsigned short* g, unsigned short* l) {
    __builtin_amdgcn_global_load_lds(
        (const __attribute__((address_space(1))) unsigned int*)g,
        (__attribute__((address_space(3))) unsigned int*)l, 16, 0, 0);
}
static __device__ __forceinline__ int fsw(int row) {
    return (row & 7) ^ ((row >> 2) & 7);
}

// ---------------- fp32 -> bf16 copy ----------------
__global__ __launch_bounds__(256) void cvt_k(const float* __restrict__ x,
                                             unsigned short* __restrict__ xb)
{
    size_t i = ((size_t)blockIdx.x * 256 + threadIdx.x) * 8;
    float4 a = *(const float4*)(x + i);
    float4 b = *(const float4*)(x + i + 4);
    uint4 p = { pack2(a.x, a.y), pack2(a.z, a.w), pack2(b.x, b.y), pack2(b.z, b.w) };
    *(uint4*)(xb + i) = p;
}

// ---------------- fp32 -> bf16: three W's in one dispatch ----------------
__global__ __launch_bounds__(256) void cvt_w3(
    const float* __restrict__ w0, const float* __restrict__ w1,
    const float* __restrict__ w2, unsigned short* __restrict__ outb)
{
    int sel = blockIdx.x >> 9;
    int blk = blockIdx.x & 511;
    const float* src = (sel == 0) ? w0 : (sel == 1) ? w1 : w2;
    size_t i = ((size_t)blk * 256 + threadIdx.x) * 8;
    float4 a = *(const float4*)(src + i);
    float4 b = *(const float4*)(src + i + 4);
    uint4 p = { pack2(a.x, a.y), pack2(a.z, a.w), pack2(b.x, b.y), pack2(b.z, b.w) };
    *(uint4*)(outb + (size_t)sel * D_MODEL * D_MODEL + i) = p;
}

// ---------------- fused QKV GEMM, 128x128 tile ----------------
// sel = blockIdx.x>>3: 0 Q (osc=0.125, per-head), 1 K (per-head), 2 V (Vt transpose).
__global__ __launch_bounds__(256) void gemm_qkv3(
    const unsigned short* __restrict__ A, const unsigned short* __restrict__ Wb3,
    const float* __restrict__ bq, const float* __restrict__ bk,
    const float* __restrict__ bv, unsigned short* __restrict__ Qh,
    unsigned short* __restrict__ Kh, unsigned short* __restrict__ Vt)
{
    __shared__ unsigned short lds[16384];    // 32 KB: lA | lB
    unsigned short* lA = lds;
    unsigned short* lB = lds + 8192;
    const int tid = threadIdx.x;
    const int wv = tid >> 6, lane = tid & 63, quad = lane >> 4, lm = lane & 15;
    const int sel = blockIdx.x >> 3;
    const int m0 = blockIdx.y * 128, n0 = (blockIdx.x & 7) * 128;
    const int sub = lane >> 3, chl = (lane & 7) ^ sub;
    const unsigned short* Wb = Wb3 + (size_t)sel * D_MODEL * D_MODEL;
    const float* bias = (sel == 0) ? bq : (sel == 1) ? bk : bv;
    const float osc = (sel == 0) ? 0.125f : 1.0f;

    f32x4 acc[2][8] = {};

    for (int k0 = 0; k0 < D_MODEL; k0 += 64) {
        __syncthreads();
#pragma unroll
        for (int j = 0; j < 4; ++j) {
            int rbase = wv * 32 + j * 8;
            gl_lds16(A + (size_t)(m0 + rbase + sub) * D_MODEL + k0 + chl * 8,
                     &lA[rbase * 64]);
            gl_lds16(Wb + (size_t)(n0 + rbase + sub) * D_MODEL + k0 + chl * 8,
                     &lB[rbase * 64]);
        }
        __syncthreads();
#pragma unroll
        for (int ks = 0; ks < 2; ++ks) {
            uint4 af[2];
#pragma unroll
            for (int mt = 0; mt < 2; ++mt)
                af[mt] = *(const uint4*)&lA[(wv * 32 + mt * 16 + lm) * 64 +
                                            ((ks * 4 + quad) ^ (lm & 7)) * 8];
#pragma unroll
            for (int nt = 0; nt < 8; ++nt) {
                uint4 bf = *(const uint4*)&lB[(nt * 16 + lm) * 64 +
                                              ((ks * 4 + quad) ^ (lm & 7)) * 8];
                acc[0][nt] = mfma16(af[0], bf, acc[0][nt]);
                acc[1][nt] = mfma16(af[1], bf, acc[1][nt]);
            }
        }
    }

    if (sel < 2) {
        unsigned short* out = (sel == 0) ? Qh : Kh;
#pragma unroll
        for (int nt = 0; nt < 8; ++nt) {
            int n = n0 + nt * 16 + lm;
            float bvv = bias[n];
            int h = n >> 6, d = n & 63;
#pragma unroll
            for (int mt = 0; mt < 2; ++mt)
#pragma unroll
                for (int r = 0; r < 4; ++r) {
                    int m = m0 + wv * 32 + mt * 16 + quad * 4 + r;
                    int b = m >> 11, q = m & 2047;
                    out[((size_t)(b * NH + h) * SEQ + q) * DKH + d] =
                        f2bf((acc[mt][nt][r] + bvv) * osc);
                }
        }
    } else {
        __syncthreads();
        unsigned short* T = lds;   // 128 n x 128 m u16 = 32 KB
#pragma unroll
        for (int nt = 0; nt < 8; ++nt) {
            float bvv = bias[n0 + nt * 16 + lm];
            int nl = nt * 16 + lm;
#pragma unroll
            for (int mt = 0; mt < 2; ++mt) {
                int ml = wv * 32 + mt * 16 + quad * 4;
                uint2 p = { pack2rn(acc[mt][nt][0] + bvv, acc[mt][nt][1] + bvv),
                            pack2rn(acc[mt][nt][2] + bvv, acc[mt][nt][3] + bvv) };
                *(uint2*)&T[nl * 128 + ml] = p;
            }
        }
        __syncthreads();
        int row = tid >> 1, seg = tid & 1;
        int b = m0 >> 11, s0 = m0 & 2047;
        unsigned short* dst = Vt + ((size_t)(b * D_MODEL) + n0 + row) * SEQ + s0 + seg * 64;
        const unsigned short* src = &T[row * 128 + seg * 64];
#pragma unroll
        for (int i = 0; i < 8; ++i)
            *(uint4*)(dst + i * 8) = *(const uint4*)(src + i * 8);
    }
}

// ---------------- psum: fold KS per-head bf16 partials ----------------
template <int KS>
__global__ __launch_bounds__(256) void psum(const unsigned short* __restrict__ OP,
                                            unsigned short* __restrict__ OPs)
{
    const size_t M = (size_t)NTOK * D_MODEL;
    size_t i = ((size_t)blockIdx.x * 256 + threadIdx.x) * 8;
    uint4 a = *(const uint4*)(OP + i);
    float lo0 = bflo(a.x), hi0 = bfhi(a.x), lo1 = bflo(a.y), hi1 = bfhi(a.y);
    float lo2 = bflo(a.z), hi2 = bfhi(a.z), lo3 = bflo(a.w), hi3 = bfhi(a.w);
#pragma unroll
    for (int p = 1; p < KS; ++p) {
        uint4 u = *(const uint4*)(OP + p * M + i);
        lo0 += bflo(u.x); hi0 += bfhi(u.x); lo1 += bflo(u.y); hi1 += bfhi(u.y);
        lo2 += bflo(u.z); hi2 += bfhi(u.z); lo3 += bflo(u.w); hi3 += bfhi(u.w);
    }
    uint4 o = { pack2(lo0, hi0), pack2(lo1, hi1), pack2(lo2, hi2), pack2(lo3, hi3) };
    *(uint4*)(OPs + i) = o;
}

// ---------------- out-proj: A = folded per-head ctx (bf16), B = Wo bf16; fp32 out ----
__global__ __launch_bounds__(256) void gemm_osum1(
    const unsigned short* __restrict__ OPs, const unsigned short* __restrict__ WoB,
    const float* __restrict__ bias, float* __restrict__ out)
{
    __shared__ unsigned short lds[16384];
    unsigned short* lA = lds;
    unsigned short* lB = lds + 8192;
    const int tid = threadIdx.x;
    const int wv = tid >> 6, lane = tid & 63, quad = lane >> 4, lm = lane & 15;
    const int m0 = blockIdx.y * 128, n0 = blockIdx.x * 128;
    const int sub = lane >> 3, chl = (lane & 7) ^ sub;
    const int b = m0 >> 11, q0 = m0 & 2047;

    f32x4 acc[2][8] = {};

    for (int k0 = 0; k0 < D_MODEL; k0 += 64) {
        const int h = k0 >> 6;
        const unsigned short* Ab = OPs + ((size_t)(b * NH + h) * SEQ + q0) * DKH;
        __syncthreads();
#pragma unroll
        for (int j = 0; j < 4; ++j) {
            int rbase = wv * 32 + j * 8;
            gl_lds16(Ab + (size_t)(rbase + sub) * DKH + chl * 8, &lA[rbase * 64]);
            gl_lds16(WoB + (size_t)(n0 + rbase + sub) * D_MODEL + k0 + chl * 8,
                     &lB[rbase * 64]);
        }
        __syncthreads();
#pragma unroll
        for (int ks = 0; ks < 2; ++ks) {
            uint4 af[2];
#pragma unroll
            for (int mt = 0; mt < 2; ++mt)
                af[mt] = *(const uint4*)&lA[(wv * 32 + mt * 16 + lm) * 64 +
                                            ((ks * 4 + quad) ^ (lm & 7)) * 8];
#pragma unroll
            for (int nt = 0; nt < 8; ++nt) {
                uint4 bf = *(const uint4*)&lB[(nt * 16 + lm) * 64 +
                                              ((ks * 4 + quad) ^ (lm & 7)) * 8];
                acc[0][nt] = mfma16(af[0], bf, acc[0][nt]);
                acc[1][nt] = mfma16(af[1], bf, acc[1][nt]);
            }
        }
    }
#pragma unroll
    for (int nt = 0; nt < 8; ++nt) {
        int n = n0 + nt * 16 + lm;
        float bv = bias[n];
#pragma unroll
        for (int mt = 0; mt < 2; ++mt)
#pragma unroll
            for (int r = 0; r < 4; ++r) {
                int m = m0 + wv * 32 + mt * 16 + quad * 4 + r;
                out[(size_t)m * D_MODEL + n] = acc[mt][nt][r] + bv;
            }
    }
}

// ---------------- zker2: rz[b][q][k] = 1/sum_h exp(S_scaled), K LDS-staged ----------------
__global__ __launch_bounds__(256) void zker2(
    const unsigned short* __restrict__ Qh, const unsigned short* __restrict__ Kh,
    unsigned short* __restrict__ rz)
{
    __shared__ unsigned short lK[128 * 64];  // 16 KB
    const int tid = threadIdx.x;
    const int wv = tid >> 6, lane = tid & 63, quad = lane >> 4, lm = lane & 15;
    const int q0 = blockIdx.x * 128, k0 = blockIdx.y * 128, b = blockIdx.z;
    const int srow = tid >> 3, sc = tid & 7;

    f32x4 z[2][8] = {};

    for (int h = 0; h < NH; ++h) {
        const size_t kb = ((size_t)(b * NH + h) * SEQ + k0) * DKH;
        __syncthreads();
#pragma unroll
        for (int j = 0; j < 4; ++j) {
            int row = j * 32 + srow;
            int g = sc ^ fsw(row);
            gl_lds16(Kh + kb + (size_t)row * 64 + g * 8, &lK[(j * 32 + wv * 8) * 64]);
        }
        uint4 bq[2][2];
#pragma unroll
        for (int qs = 0; qs < 2; ++qs) {
            const unsigned short* qp = Qh +
                ((size_t)(b * NH + h) * SEQ + q0 + wv * 32 + qs * 16 + lm) * DKH + quad * 8;
            bq[qs][0] = *(const uint4*)qp;
            bq[qs][1] = *(const uint4*)(qp + 32);
        }
        __syncthreads();
#pragma unroll
        for (int kt = 0; kt < 8; ++kt) {
            int krow = kt * 16 + lm;
            uint4 a0 = *(const uint4*)&lK[krow * 64 + ((quad) ^ fsw(krow)) * 8];
            uint4 a1 = *(const uint4*)&lK[krow * 64 + ((4 + quad) ^ fsw(krow)) * 8];
#pragma unroll
            for (int qs = 0; qs < 2; ++qs) {
                f32x4 sf = {0.f, 0.f, 0.f, 0.f};
                sf = mfma16(a0, bq[qs][0], sf);
                sf = mfma16(a1, bq[qs][1], sf);
#pragma unroll
                for (int r = 0; r < 4; ++r)
                    z[qs][kt][r] += __expf(sf[r]);
            }
        }
    }
#pragma unroll
    for (int qs = 0; qs < 2; ++qs) {
        int q = q0 + wv * 32 + qs * 16 + lm;
#pragma unroll
        for (int kt = 0; kt < 8; ++kt) {
            int k = k0 + kt * 16 + quad * 4;
            uint2 st = { pack2rn(1.0f / z[qs][kt][0], 1.0f / z[qs][kt][1]),
                         pack2rn(1.0f / z[qs][kt][2], 1.0f / z[qs][kt][3]) };
            *(uint2*)(rz + (size_t)(b * SEQ + q) * SEQ + k) = st;
        }
    }
}

// ---------------- attn4: per-head attention; K/Vt LDS-staged, rz direct ----------------
template <int KS>
__global__ __launch_bounds__(256) void attn4(
    const unsigned short* __restrict__ Qh, const unsigned short* __restrict__ Kh,
    const unsigned short* __restrict__ Vt, const unsigned short* __restrict__ rz,
    unsigned short* __restrict__ OP)
{
    __shared__ unsigned short lK[64 * 64];   // 8 KB
    __shared__ unsigned short lV[64 * 64];   // 8 KB
    const int tid = threadIdx.x;
    const int wv = tid >> 6, lane = tid & 63, quad = lane >> 4, lm = lane & 15;
    const int q0 = blockIdx.x * 128;
    const int bh = blockIdx.y, b = bh >> 4, h = bh & 15;
    const int ksl = blockIdx.z;
    const int NIT = (SEQ / KS) / 64;
    const int kbeg = ksl * (SEQ / KS);
    const int q0w = q0 + wv * 32;
    const size_t hb = (size_t)(b * NH + h) * SEQ;
    const int srow = tid >> 3, sc = tid & 7;

    uint4 qf[2][2];
#pragma unroll
    for (int qs = 0; qs < 2; ++qs)
#pragma unroll
        for (int ks = 0; ks < 2; ++ks)
            qf[qs][ks] = *(const uint4*)(Qh + (hb + q0w + qs * 16 + lm) * DKH +
                                         ks * 32 + quad * 8);

    const int perm = ((lm >> 2) * 8) + (lm & 3);
    f32x4 oa[4][2] = {};

    for (int kt = 0; kt < NIT; ++kt) {
        const int kbase = kbeg + kt * 64;
        __syncthreads();
#pragma unroll
        for (int j = 0; j < 2; ++j) {
            int row = j * 32 + srow;
            int g = sc ^ fsw(row);
            gl_lds16(Kh + (hb + kbase + row) * DKH + g * 8,
                     &lK[(j * 32 + wv * 8) * 64]);
        }
#pragma unroll
        for (int j = 0; j < 2; ++j) {
            int row = j * 32 + srow;
            int g = sc ^ fsw(row);
            gl_lds16(Vt + ((size_t)(b * D_MODEL) + h * DKH + row) * SEQ + kbase + g * 8,
                     &lV[(j * 32 + wv * 8) * 64]);
        }
        uint4 rv[2][2];
#pragma unroll
        for (int qs = 0; qs < 2; ++qs)
#pragma unroll
            for (int gr = 0; gr < 2; ++gr)
                rv[gr][qs] = *(const uint4*)(rz +
                    (size_t)(b * SEQ + q0w + qs * 16 + lm) * SEQ +
                    kbase + gr * 32 + quad * 8);
        __syncthreads();

#pragma unroll
        for (int gr = 0; gr < 2; ++gr) {
            f32x4 sf[2][2] = {};
#pragma unroll
            for (int sel = 0; sel < 2; ++sel) {
                int key = gr * 32 + perm + sel * 4;
#pragma unroll
                for (int ks = 0; ks < 2; ++ks) {
                    uint4 kfv = *(const uint4*)&lK[key * 64 +
                                                   ((ks * 4 + quad) ^ fsw(key)) * 8];
                    sf[sel][0] = mfma16(kfv, qf[0][ks], sf[sel][0]);
                    sf[sel][1] = mfma16(kfv, qf[1][ks], sf[sel][1]);
                }
            }
            uint4 pk[2];
#pragma unroll
            for (int qs = 0; qs < 2; ++qs) {
                uint4 rq = rv[gr][qs];
                float p00 = __expf(sf[0][qs][0]) * bflo(rq.x);
                float p01 = __expf(sf[0][qs][1]) * bfhi(rq.x);
                float p02 = __expf(sf[0][qs][2]) * bflo(rq.y);
                float p03 = __expf(sf[0][qs][3]) * bfhi(rq.y);
                float p10 = __expf(sf[1][qs][0]) * bflo(rq.z);
                float p11 = __expf(sf[1][qs][1]) * bfhi(rq.z);
                float p12 = __expf(sf[1][qs][2]) * bflo(rq.w);
                float p13 = __expf(sf[1][qs][3]) * bfhi(rq.w);
                pk[qs].x = pack2rn(p00, p01);
                pk[qs].y = pack2rn(p02, p03);
                pk[qs].z = pack2rn(p10, p11);
                pk[qs].w = pack2rn(p12, p13);
            }
#pragma unroll
            for (int ct = 0; ct < 4; ++ct) {
                int vrow = ct * 16 + lm;
                uint4 vfv = *(const uint4*)&lV[vrow * 64 +
                                               ((gr * 4 + quad) ^ fsw(vrow)) * 8];
                oa[ct][0] = mfma16(vfv, pk[0], oa[ct][0]);
                oa[ct][1] = mfma16(vfv, pk[1], oa[ct][1]);
            }
        }
    }

    unsigned short* op = OP + (size_t)ksl * NTOK * D_MODEL;
#pragma unroll
    for (int ct = 0; ct < 4; ++ct)
#pragma unroll
        for (int qs = 0; qs < 2; ++qs) {
            uint2 st = { pack2rn(oa[ct][qs][0], oa[ct][qs][1]),
                         pack2rn(oa[ct][qs][2], oa[ct][qs][3]) };
            *(uint2*)(op + (hb + q0w + qs * 16 + lm) * DKH + ct * 16 + quad * 4) = st;
        }
}

extern "C" void kernel_launch(void* const* d_in, const int* in_sizes, int n_in,
                              void* d_out, int out_size, void* d_ws, size_t ws_size,
                              hipStream_t stream)
{
    const float* x  = (const float*)d_in[0];
    const float* Wq = (const float*)d_in[1];
    const float* bq = (const float*)d_in[2];
    const float* Wk = (const float*)d_in[3];
    const float* bk = (const float*)d_in[4];
    const float* Wv = (const float*)d_in[5];
    const float* bv = (const float*)d_in[6];
    const float* Wo = (const float*)d_in[7];
    const float* bo = (const float*)d_in[8];
    float* out = (float*)d_out;

    const size_t M  = (size_t)NTOK * D_MODEL;      // 4,194,304
    const size_t RZ = (size_t)NB * SEQ * SEQ;      // 8,388,608
    unsigned short* ws = (unsigned short*)d_ws;
    unsigned short* rzb = ws;            // rz; also xb early, WoB late (both dead overlaps)
    unsigned short* xb  = ws;
    unsigned short* Qh  = ws + RZ;       // per-head [(b,h,q)][dk], Q pre-scaled by 1/8
    unsigned short* Kh  = Qh + M;
    unsigned short* Vt  = Kh + M;        // [b][c][s]
    unsigned short* OP  = Vt + M;        // KS per-head partials; early alias: Wb3
    unsigned short* Wb3 = OP;
    unsigned short* OPs = Qh;            // folded ctx (Qh dead after attn4)
    unsigned short* WoB = rzb;           // bf16 Wo (rz dead after attn4)

    const size_t need4 = (RZ + 3 * M + 4 * M) * sizeof(unsigned short);  // 75.5 MB
    const size_t need2 = (RZ + 3 * M + 2 * M) * sizeof(unsigned short);  // 58.7 MB
    const int KS = (ws_size >= need4) ? 4 : (ws_size >= need2) ? 2 : 1;

    cvt_k<<<2048, 256, 0, stream>>>(x, xb);
    cvt_w3<<<1536, 256, 0, stream>>>(Wq, Wk, Wv, Wb3);
    gemm_qkv3<<<dim3(24, 32), 256, 0, stream>>>(xb, Wb3, bq, bk, bv, Qh, Kh, Vt);
    zker2<<<dim3(16, 16, NB), 256, 0, stream>>>(Qh, Kh, rzb);
    if (KS == 4)      attn4<4><<<dim3(16, NB * NH, 4), 256, 0, stream>>>(Qh, Kh, Vt, rzb, OP);
    else if (KS == 2) attn4<2><<<dim3(16, NB * NH, 2), 256, 0, stream>>>(Qh, Kh, Vt, rzb, OP);
    else              attn4<1><<<dim3(16, NB * NH, 1), 256, 0, stream>>>(Qh, Kh, Vt, rzb, OP);
    cvt_k<<<512, 256, 0, stream>>>(Wo, WoB);     // rz dead now
    if (KS == 4)      psum<4><<<2048, 256, 0, stream>>>(OP, OPs);
    else if (KS == 2) psum<2><<<2048, 256, 0, stream>>>(OP, OPs);
    else              OPs = OP;
    gemm_osum1<<<dim3(8, 32), 256, 0, stream>>>(OPs, WoB, bo, out);
}

// Round 9
// 268.060 us; speedup vs baseline: 1.2067x; 1.0327x over previous
//
#include <hip/hip_runtime.h>

// MultiHeadattention: B=2, S=2048, D=1024, H=16, Dk=64.
// QUIRK: softmax over the HEAD axis (dim=1): attn[b,h,q,k] = exp(s)/sum_h' exp(s').
// R9: (1) log-space softmax: Q pre-scaled by 0.125*log2e; zker2 stores lrz=-log2(Z);
// attn4 initializes QK MFMA C with lrz -> p = exp2(sf) raw v_exp_f32 (no muls);
// truncating 1-inst P packs. (2) XCD-aware block swizzle in attn4/zker2 so blocks
// sharing K/V slabs land on one XCD (R8 FETCH 85MB ~= 8x slab duplication).

#define D_MODEL 1024
#define NH 16
#define DKH 64
#define SEQ 2048
#define NB 2
#define NTOK (NB * SEQ)
#define OSC 0.180336880f   // 0.125 * log2(e)

typedef float f32x4 __attribute__((ext_vector_type(4)));
typedef short bf16x8 __attribute__((ext_vector_type(8)));

static __device__ __forceinline__ unsigned short f2bf(float x) {
    union { float f; unsigned int u; } c; c.f = x;
    unsigned int r = (c.u + 0x7FFFu + ((c.u >> 16) & 1u)) >> 16;
    return (unsigned short)r;
}
static __device__ __forceinline__ unsigned int pack2(float a, float b) {
    return (unsigned int)f2bf(a) | ((unsigned int)f2bf(b) << 16);
}
static __device__ __forceinline__ unsigned int pack2rn(float a, float b) {
    union { float f; unsigned int u; } ca, cb; ca.f = a; cb.f = b;
    return __builtin_amdgcn_perm(cb.u + 0x8000u, ca.u + 0x8000u, 0x07060302u);
}
// truncating pack (1 inst) — inner-loop P only (P>0, bias ~2^-9)
static __device__ __forceinline__ unsigned int pack2tr(float a, float b) {
    union { float f; unsigned int u; } ca, cb; ca.f = a; cb.f = b;
    return __builtin_amdgcn_perm(cb.u, ca.u, 0x07060302u);
}
static __device__ __forceinline__ float bflo(unsigned int u) {
    union { unsigned int x; float f; } c; c.x = u << 16; return c.f;
}
static __device__ __forceinline__ float bfhi(unsigned int u) {
    union { unsigned int x; float f; } c; c.x = u & 0xFFFF0000u; return c.f;
}
static __device__ __forceinline__ f32x4 mfma16(uint4 a, uint4 b, f32x4 c) {
    return __builtin_amdgcn_mfma_f32_16x16x32_bf16(
        __builtin_bit_cast(bf16x8, a), __builtin_bit_cast(bf16x8, b), c, 0, 0, 0);
}
static __device__ __forceinline__ void gl_lds16(const unsigned short* g, unsigned short* l) {
    __builtin_amdgcn_global_load_lds(
        (const __attribute__((address_space(1))) unsigned int*)g,
        (__attribute__((address_space(3))) unsigned int*)l, 16, 0, 0);
}
static __device__ __forceinline__ int fsw(int row) {
    return (row & 7) ^ ((row >> 2) & 7);
}

// ---------------- fp32 -> bf16 copy ----------------
__global__ __launch_bounds__(256) void cvt_k(const float* __restrict__ x,
                                             unsigned short* __restrict__ xb)
{
    size_t i = ((size_t)blockIdx.x * 256 + threadIdx.x) * 8;
    float4 a = *(const float4*)(x + i);
    float4 b = *(const float4*)(x + i + 4);
    uint4 p = { pack2(a.x, a.y), pack2(a.z, a.w), pack2(b.x, b.y), pack2(b.z, b.w) };
    *(uint4*)(xb + i) = p;
}

// ---------------- fp32 -> bf16: three W's in one dispatch ----------------
__global__ __launch_bounds__(256) void cvt_w3(
    const float* __restrict__ w0, const float* __restrict__ w1,
    const float* __restrict__ w2, unsigned short* __restrict__ outb)
{
    int sel = blockIdx.x >> 9;
    int blk = blockIdx.x & 511;
    const float* src = (sel == 0) ? w0 : (sel == 1) ? w1 : w2;
    size_t i = ((size_t)blk * 256 + threadIdx.x) * 8;
    float4 a = *(const float4*)(src + i);
    float4 b = *(const float4*)(src + i + 4);
    uint4 p = { pack2(a.x, a.y), pack2(a.z, a.w), pack2(b.x, b.y), pack2(b.z, b.w) };
    *(uint4*)(outb + (size_t)sel * D_MODEL * D_MODEL + i) = p;
}

// ---------------- fused QKV GEMM, 128x128 tile ----------------
// sel: 0 Q (osc=OSC, per-head), 1 K (per-head), 2 V (Vt transpose).
__global__ __launch_bounds__(256) void gemm_qkv3(
    const unsigned short* __restrict__ A, const unsigned short* __restrict__ Wb3,
    const float* __restrict__ bq, const float* __restrict__ bk,
    const float* __restrict__ bv, unsigned short* __restrict__ Qh,
    unsigned short* __restrict__ Kh, unsigned short* __restrict__ Vt)
{
    __shared__ unsigned short lds[16384];    // 32 KB: lA | lB
    unsigned short* lA = lds;
    unsigned short* lB = lds + 8192;
    const int tid = threadIdx.x;
    const int wv = tid >> 6, lane = tid & 63, quad = lane >> 4, lm = lane & 15;
    const int sel = blockIdx.x >> 3;
    const int m0 = blockIdx.y * 128, n0 = (blockIdx.x & 7) * 128;
    const int sub = lane >> 3, chl = (lane & 7) ^ sub;
    const unsigned short* Wb = Wb3 + (size_t)sel * D_MODEL * D_MODEL;
    const float* bias = (sel == 0) ? bq : (sel == 1) ? bk : bv;
    const float osc = (sel == 0) ? OSC : 1.0f;

    f32x4 acc[2][8] = {};

    for (int k0 = 0; k0 < D_MODEL; k0 += 64) {
        __syncthreads();
#pragma unroll
        for (int j = 0; j < 4; ++j) {
            int rbase = wv * 32 + j * 8;
            gl_lds16(A + (size_t)(m0 + rbase + sub) * D_MODEL + k0 + chl * 8,
                     &lA[rbase * 64]);
            gl_lds16(Wb + (size_t)(n0 + rbase + sub) * D_MODEL + k0 + chl * 8,
                     &lB[rbase * 64]);
        }
        __syncthreads();
#pragma unroll
        for (int ks = 0; ks < 2; ++ks) {
            uint4 af[2];
#pragma unroll
            for (int mt = 0; mt < 2; ++mt)
                af[mt] = *(const uint4*)&lA[(wv * 32 + mt * 16 + lm) * 64 +
                                            ((ks * 4 + quad) ^ (lm & 7)) * 8];
#pragma unroll
            for (int nt = 0; nt < 8; ++nt) {
                uint4 bf = *(const uint4*)&lB[(nt * 16 + lm) * 64 +
                                              ((ks * 4 + quad) ^ (lm & 7)) * 8];
                acc[0][nt] = mfma16(af[0], bf, acc[0][nt]);
                acc[1][nt] = mfma16(af[1], bf, acc[1][nt]);
            }
        }
    }

    if (sel < 2) {
        unsigned short* out = (sel == 0) ? Qh : Kh;
#pragma unroll
        for (int nt = 0; nt < 8; ++nt) {
            int n = n0 + nt * 16 + lm;
            float bvv = bias[n];
            int h = n >> 6, d = n & 63;
#pragma unroll
            for (int mt = 0; mt < 2; ++mt)
#pragma unroll
                for (int r = 0; r < 4; ++r) {
                    int m = m0 + wv * 32 + mt * 16 + quad * 4 + r;
                    int b = m >> 11, q = m & 2047;
                    out[((size_t)(b * NH + h) * SEQ + q) * DKH + d] =
                        f2bf((acc[mt][nt][r] + bvv) * osc);
                }
        }
    } else {
        __syncthreads();
        unsigned short* T = lds;   // 128 n x 128 m u16
#pragma unroll
        for (int nt = 0; nt < 8; ++nt) {
            float bvv = bias[n0 + nt * 16 + lm];
            int nl = nt * 16 + lm;
#pragma unroll
            for (int mt = 0; mt < 2; ++mt) {
                int ml = wv * 32 + mt * 16 + quad * 4;
                uint2 p = { pack2rn(acc[mt][nt][0] + bvv, acc[mt][nt][1] + bvv),
                            pack2rn(acc[mt][nt][2] + bvv, acc[mt][nt][3] + bvv) };
                *(uint2*)&T[nl * 128 + ml] = p;
            }
        }
        __syncthreads();
        int row = tid >> 1, seg = tid & 1;
        int b = m0 >> 11, s0 = m0 & 2047;
        unsigned short* dst = Vt + ((size_t)(b * D_MODEL) + n0 + row) * SEQ + s0 + seg * 64;
        const unsigned short* src = &T[row * 128 + seg * 64];
#pragma unroll
        for (int i = 0; i < 8; ++i)
            *(uint4*)(dst + i * 8) = *(const uint4*)(src + i * 8);
    }
}

// ---------------- psum: fold KS per-head bf16 partials ----------------
template <int KS>
__global__ __launch_bounds__(256) void psum(const unsigned short* __restrict__ OP,
                                            unsigned short* __restrict__ OPs)
{
    const size_t M = (size_t)NTOK * D_MODEL;
    size_t i = ((size_t)blockIdx.x * 256 + threadIdx.x) * 8;
    uint4 a = *(const uint4*)(OP + i);
    float lo0 = bflo(a.x), hi0 = bfhi(a.x), lo1 = bflo(a.y), hi1 = bfhi(a.y);
    float lo2 = bflo(a.z), hi2 = bfhi(a.z), lo3 = bflo(a.w), hi3 = bfhi(a.w);
#pragma unroll
    for (int p = 1; p < KS; ++p) {
        uint4 u = *(const uint4*)(OP + p * M + i);
        lo0 += bflo(u.x); hi0 += bfhi(u.x); lo1 += bflo(u.y); hi1 += bfhi(u.y);
        lo2 += bflo(u.z); hi2 += bfhi(u.z); lo3 += bflo(u.w); hi3 += bfhi(u.w);
    }
    uint4 o = { pack2(lo0, hi0), pack2(lo1, hi1), pack2(lo2, hi2), pack2(lo3, hi3) };
    *(uint4*)(OPs + i) = o;
}

// ---------------- out-proj: A = folded ctx (bf16), B = Wo bf16; fp32 out ----------------
__global__ __launch_bounds__(256) void gemm_osum1(
    const unsigned short* __restrict__ OPs, const unsigned short* __restrict__ WoB,
    const float* __restrict__ bias, float* __restrict__ out)
{
    __shared__ unsigned short lds[16384];
    unsigned short* lA = lds;
    unsigned short* lB = lds + 8192;
    const int tid = threadIdx.x;
    const int wv = tid >> 6, lane = tid & 63, quad = lane >> 4, lm = lane & 15;
    const int m0 = blockIdx.y * 128, n0 = blockIdx.x * 128;
    const int sub = lane >> 3, chl = (lane & 7) ^ sub;
    const int b = m0 >> 11, q0 = m0 & 2047;

    f32x4 acc[2][8] = {};

    for (int k0 = 0; k0 < D_MODEL; k0 += 64) {
        const int h = k0 >> 6;
        const unsigned short* Ab = OPs + ((size_t)(b * NH + h) * SEQ + q0) * DKH;
        __syncthreads();
#pragma unroll
        for (int j = 0; j < 4; ++j) {
            int rbase = wv * 32 + j * 8;
            gl_lds16(Ab + (size_t)(rbase + sub) * DKH + chl * 8, &lA[rbase * 64]);
            gl_lds16(WoB + (size_t)(n0 + rbase + sub) * D_MODEL + k0 + chl * 8,
                     &lB[rbase * 64]);
        }
        __syncthreads();
#pragma unroll
        for (int ks = 0; ks < 2; ++ks) {
            uint4 af[2];
#pragma unroll
            for (int mt = 0; mt < 2; ++mt)
                af[mt] = *(const uint4*)&lA[(wv * 32 + mt * 16 + lm) * 64 +
                                            ((ks * 4 + quad) ^ (lm & 7)) * 8];
#pragma unroll
            for (int nt = 0; nt < 8; ++nt) {
                uint4 bf = *(const uint4*)&lB[(nt * 16 + lm) * 64 +
                                              ((ks * 4 + quad) ^ (lm & 7)) * 8];
                acc[0][nt] = mfma16(af[0], bf, acc[0][nt]);
                acc[1][nt] = mfma16(af[1], bf, acc[1][nt]);
            }
        }
    }
#pragma unroll
    for (int nt = 0; nt < 8; ++nt) {
        int n = n0 + nt * 16 + lm;
        float bv = bias[n];
#pragma unroll
        for (int mt = 0; mt < 2; ++mt)
#pragma unroll
            for (int r = 0; r < 4; ++r) {
                int m = m0 + wv * 32 + mt * 16 + quad * 4 + r;
                out[(size_t)m * D_MODEL + n] = acc[mt][nt][r] + bv;
            }
    }
}

// ---------------- zker2: lrz[b][q][k] = -log2(sum_h exp2(S_scaled)), XCD-swizzled ----
__global__ __launch_bounds__(256) void zker2(
    const unsigned short* __restrict__ Qh, const unsigned short* __restrict__ Kh,
    unsigned short* __restrict__ rz)
{
    __shared__ unsigned short lK[128 * 64];  // 16 KB
    const int tid = threadIdx.x;
    const int wv = tid >> 6, lane = tid & 63, quad = lane >> 4, lm = lane & 15;
    // swizzle: XCD owns 4 (b,kb) columns x all 16 qb (qb adjacent -> K slab shared)
    const int lid = blockIdx.x;
    const int xcd = lid & 7, slot = lid >> 3;
    const int qb = slot & 15, col = xcd * 4 + (slot >> 4);
    const int b = col >> 4, kb = col & 15;
    const int q0 = qb * 128, k0 = kb * 128;
    const int srow = tid >> 3, sc = tid & 7;

    f32x4 z[2][8] = {};

    for (int h = 0; h < NH; ++h) {
        const size_t kbase = ((size_t)(b * NH + h) * SEQ + k0) * DKH;
        __syncthreads();
#pragma unroll
        for (int j = 0; j < 4; ++j) {
            int row = j * 32 + srow;
            int g = sc ^ fsw(row);
            gl_lds16(Kh + kbase + (size_t)row * 64 + g * 8, &lK[(j * 32 + wv * 8) * 64]);
        }
        uint4 bq[2][2];
#pragma unroll
        for (int qs = 0; qs < 2; ++qs) {
            const unsigned short* qp = Qh +
                ((size_t)(b * NH + h) * SEQ + q0 + wv * 32 + qs * 16 + lm) * DKH + quad * 8;
            bq[qs][0] = *(const uint4*)qp;
            bq[qs][1] = *(const uint4*)(qp + 32);
        }
        __syncthreads();
#pragma unroll
        for (int kt = 0; kt < 8; ++kt) {
            int krow = kt * 16 + lm;
            uint4 a0 = *(const uint4*)&lK[krow * 64 + ((quad) ^ fsw(krow)) * 8];
            uint4 a1 = *(const uint4*)&lK[krow * 64 + ((4 + quad) ^ fsw(krow)) * 8];
#pragma unroll
            for (int qs = 0; qs < 2; ++qs) {
                f32x4 sf = {0.f, 0.f, 0.f, 0.f};
                sf = mfma16(a0, bq[qs][0], sf);
                sf = mfma16(a1, bq[qs][1], sf);
#pragma unroll
                for (int r = 0; r < 4; ++r)
                    z[qs][kt][r] += __builtin_amdgcn_exp2f(sf[r]);
            }
        }
    }
#pragma unroll
    for (int qs = 0; qs < 2; ++qs) {
        int q = q0 + wv * 32 + qs * 16 + lm;
#pragma unroll
        for (int kt = 0; kt < 8; ++kt) {
            int k = k0 + kt * 16 + quad * 4;
            float l0 = __builtin_amdgcn_logf(z[qs][kt][0]);
            float l1 = __builtin_amdgcn_logf(z[qs][kt][1]);
            float l2 = __builtin_amdgcn_logf(z[qs][kt][2]);
            float l3 = __builtin_amdgcn_logf(z[qs][kt][3]);
            uint2 st = { pack2rn(-l0, -l1), pack2rn(-l2, -l3) };
            *(uint2*)(rz + (size_t)(b * SEQ + q) * SEQ + k) = st;
        }
    }
}

// ---------------- attn4: per-head attention; lrz as MFMA C-init; XCD-swizzled ----------
template <int KS>
__global__ __launch_bounds__(256) void attn4(
    const unsigned short* __restrict__ Qh, const unsigned short* __restrict__ Kh,
    const unsigned short* __restrict__ Vt, const unsigned short* __restrict__ rz,
    unsigned short* __restrict__ OP)
{
    __shared__ unsigned short lK[64 * 64];   // 8 KB
    __shared__ unsigned short lV[64 * 64];   // 8 KB
    const int tid = threadIdx.x;
    const int wv = tid >> 6, lane = tid & 63, quad = lane >> 4, lm = lane & 15;
    // swizzle: XCD owns 4*KS (bh,ksl) combos x all 16 qb (qb adjacent -> K/V slab shared)
    const int lid = blockIdx.x;
    const int xcd = lid & 7, slot = lid >> 3;
    const int qb = slot & 15;
    const int combo = xcd * (4 * KS) + (slot >> 4);
    const int bh = combo / KS, ksl = combo % KS;
    const int b = bh >> 4, h = bh & 15;
    const int q0 = qb * 128;
    const int NIT = (SEQ / KS) / 64;
    const int kbeg = ksl * (SEQ / KS);
    const int q0w = q0 + wv * 32;
    const size_t hb = (size_t)(b * NH + h) * SEQ;
    const int srow = tid >> 3, sc = tid & 7;

    uint4 qf[2][2];
#pragma unroll
    for (int qs = 0; qs < 2; ++qs)
#pragma unroll
        for (int ks = 0; ks < 2; ++ks)
            qf[qs][ks] = *(const uint4*)(Qh + (hb + q0w + qs * 16 + lm) * DKH +
                                         ks * 32 + quad * 8);

    const int perm = ((lm >> 2) * 8) + (lm & 3);
    f32x4 oa[4][2] = {};

    for (int kt = 0; kt < NIT; ++kt) {
        const int kbase = kbeg + kt * 64;
        __syncthreads();
#pragma unroll
        for (int j = 0; j < 2; ++j) {
            int row = j * 32 + srow;
            int g = sc ^ fsw(row);
            gl_lds16(Kh + (hb + kbase + row) * DKH + g * 8,
                     &lK[(j * 32 + wv * 8) * 64]);
        }
#pragma unroll
        for (int j = 0; j < 2; ++j) {
            int row = j * 32 + srow;
            int g = sc ^ fsw(row);
            gl_lds16(Vt + ((size_t)(b * D_MODEL) + h * DKH + row) * SEQ + kbase + g * 8,
                     &lV[(j * 32 + wv * 8) * 64]);
        }
        uint4 rv[2][2];
#pragma unroll
        for (int qs = 0; qs < 2; ++qs)
#pragma unroll
            for (int gr = 0; gr < 2; ++gr)
                rv[gr][qs] = *(const uint4*)(rz +
                    (size_t)(b * SEQ + q0w + qs * 16 + lm) * SEQ +
                    kbase + gr * 32 + quad * 8);
        __syncthreads();

#pragma unroll
        for (int gr = 0; gr < 2; ++gr) {
            // C-init with lrz: sf = QK^T_scaled - log2(Z); then p = exp2(sf)
            f32x4 sf[2][2];
#pragma unroll
            for (int qs = 0; qs < 2; ++qs) {
                uint4 rq = rv[gr][qs];
                sf[0][qs][0] = bflo(rq.x); sf[0][qs][1] = bfhi(rq.x);
                sf[0][qs][2] = bflo(rq.y); sf[0][qs][3] = bfhi(rq.y);
                sf[1][qs][0] = bflo(rq.z); sf[1][qs][1] = bfhi(rq.z);
                sf[1][qs][2] = bflo(rq.w); sf[1][qs][3] = bfhi(rq.w);
            }
#pragma unroll
            for (int sel = 0; sel < 2; ++sel) {
                int key = gr * 32 + perm + sel * 4;
#pragma unroll
                for (int ks = 0; ks < 2; ++ks) {
                    uint4 kfv = *(const uint4*)&lK[key * 64 +
                                                   ((ks * 4 + quad) ^ fsw(key)) * 8];
                    sf[sel][0] = mfma16(kfv, qf[0][ks], sf[sel][0]);
                    sf[sel][1] = mfma16(kfv, qf[1][ks], sf[sel][1]);
                }
            }
            uint4 pk[2];
#pragma unroll
            for (int qs = 0; qs < 2; ++qs) {
                float p00 = __builtin_amdgcn_exp2f(sf[0][qs][0]);
                float p01 = __builtin_amdgcn_exp2f(sf[0][qs][1]);
                float p02 = __builtin_amdgcn_exp2f(sf[0][qs][2]);
                float p03 = __builtin_amdgcn_exp2f(sf[0][qs][3]);
                float p10 = __builtin_amdgcn_exp2f(sf[1][qs][0]);
                float p11 = __builtin_amdgcn_exp2f(sf[1][qs][1]);
                float p12 = __builtin_amdgcn_exp2f(sf[1][qs][2]);
                float p13 = __builtin_amdgcn_exp2f(sf[1][qs][3]);
                pk[qs].x = pack2tr(p00, p01);
                pk[qs].y = pack2tr(p02, p03);
                pk[qs].z = pack2tr(p10, p11);
                pk[qs].w = pack2tr(p12, p13);
            }
#pragma unroll
            for (int ct = 0; ct < 4; ++ct) {
                int vrow = ct * 16 + lm;
                uint4 vfv = *(const uint4*)&lV[vrow * 64 +
                                               ((gr * 4 + quad) ^ fsw(vrow)) * 8];
                oa[ct][0] = mfma16(vfv, pk[0], oa[ct][0]);
                oa[ct][1] = mfma16(vfv, pk[1], oa[ct][1]);
            }
        }
    }

    unsigned short* op = OP + (size_t)ksl * NTOK * D_MODEL;
#pragma unroll
    for (int ct = 0; ct < 4; ++ct)
#pragma unroll
        for (int qs = 0; qs < 2; ++qs) {
            uint2 st = { pack2rn(oa[ct][qs][0], oa[ct][qs][1]),
                         pack2rn(oa[ct][qs][2], oa[ct][qs][3]) };
            *(uint2*)(op + (hb + q0w + qs * 16 + lm) * DKH + ct * 16 + quad * 4) = st;
        }
}

extern "C" void kernel_launch(void* const* d_in, const int* in_sizes, int n_in,
                              void* d_out, int out_size, void* d_ws, size_t ws_size,
                              hipStream_t stream)
{
    const float* x  = (const float*)d_in[0];
    const float* Wq = (const float*)d_in[1];
    const float* bq = (const float*)d_in[2];
    const float* Wk = (const float*)d_in[3];
    const float* bk = (const float*)d_in[4];
    const float* Wv = (const float*)d_in[5];
    const float* bv = (const float*)d_in[6];
    const float* Wo = (const float*)d_in[7];
    const float* bo = (const float*)d_in[8];
    float* out = (float*)d_out;

    const size_t M  = (size_t)NTOK * D_MODEL;      // 4,194,304
    const size_t RZ = (size_t)NB * SEQ * SEQ;      // 8,388,608
    unsigned short* ws = (unsigned short*)d_ws;
    unsigned short* rzb = ws;            // lrz; also xb early, WoB late
    unsigned short* xb  = ws;
    unsigned short* Qh  = ws + RZ;       // per-head [(b,h,q)][dk], Q pre-scaled by OSC
    unsigned short* Kh  = Qh + M;
    unsigned short* Vt  = Kh + M;        // [b][c][s]
    unsigned short* OP  = Vt + M;        // KS per-head partials; early alias: Wb3
    unsigned short* Wb3 = OP;
    unsigned short* OPs = Qh;            // folded ctx (Qh dead after attn4)
    unsigned short* WoB = rzb;           // bf16 Wo (lrz dead after attn4)

    const size_t need4 = (RZ + 3 * M + 4 * M) * sizeof(unsigned short);  // 75.5 MB
    const size_t need2 = (RZ + 3 * M + 2 * M) * sizeof(unsigned short);  // 58.7 MB
    const int KS = (ws_size >= need4) ? 4 : (ws_size >= need2) ? 2 : 1;

    cvt_k<<<2048, 256, 0, stream>>>(x, xb);
    cvt_w3<<<1536, 256, 0, stream>>>(Wq, Wk, Wv, Wb3);
    gemm_qkv3<<<dim3(24, 32), 256, 0, stream>>>(xb, Wb3, bq, bk, bv, Qh, Kh, Vt);
    zker2<<<512, 256, 0, stream>>>(Qh, Kh, rzb);
    if (KS == 4)      attn4<4><<<2048, 256, 0, stream>>>(Qh, Kh, Vt, rzb, OP);
    else if (KS == 2) attn4<2><<<1024, 256, 0, stream>>>(Qh, Kh, Vt, rzb, OP);
    else              attn4<1><<<512, 256, 0, stream>>>(Qh, Kh, Vt, rzb, OP);
    cvt_k<<<512, 256, 0, stream>>>(Wo, WoB);
    if (KS == 4)      psum<4><<<2048, 256, 0, stream>>>(OP, OPs);
    else if (KS == 2) psum<2><<<2048, 256, 0, stream>>>(OP, OPs);
    else              OPs = OP;
    gemm_osum1<<<dim3(8, 32), 256, 0, stream>>>(OPs, WoB, bo, out);
}